// Round 8
// baseline (339.266 us; speedup 1.0000x reference)
//
#include <hip/hip_runtime.h>
#include <hip/hip_bf16.h>

// ---------------------------------------------------------------------------
// GCN encoder: h1 = relu(P (x W1) + b1); mu = P (h1 Wmu) + bmu; ls likewise.
// P = D^-1/2 (A + I) D^-1/2, in-degree D.
// R13: R11 pipeline (best verified 319.5us) + 2-slice channel split on props.
//   Facts: prop FETCH 194MB = 8 XCDs x 24MB replication @ ~3.6TB/s fabric
//   ceiling (R6/R11/R12); slicing collapses replication (R7: FETCH->40MB)
//   but every restructured engine lost to latency (R8-R10); R12 fusion of
//   non-prop stages regressed (+15us) -> reverted.
//   R13 = the untried quadrant: slicing with the PROVEN R11 engine intact.
//   H tables [2][n][64ch] (128-B rows); prop grid x2, slice = bid&1 so
//   slice 0 lives on XCDs {0,2,4,6}, slice 1 on {1,3,5,7} (bid%8 RR) ->
//   per-XCD footprint 25.6 -> 12.8MB. Same wave-pair engine, uint gathers
//   (2ch/lane), esrc nt-protected. GEMM1 store / GEMM2 A-read re-indexed.
// ---------------------------------------------------------------------------

#define BW_SH   8                 // bucket width = 256 targets
#define BW      (1 << BW_SH)
#define NBUCK_MAX 512             // supports n <= 131072
#define EPB     6144              // edges per bucket-pass block
#define CAP     5120              // per-bucket segment slots (mean 4092, sd 64)
#define GPAD    16                // gcur stride in ints (64B line per counter)

typedef __attribute__((ext_vector_type(8))) short bf16x8;
typedef __attribute__((ext_vector_type(4))) float f32x4;

__device__ __forceinline__ unsigned bf16rne(float f) {   // fp32 -> bf16 bits (RNE)
    unsigned u = __float_as_uint(f);
    return (u + 0x7fffu + ((u >> 16) & 1u)) >> 16;
}
__device__ __forceinline__ float bflo(unsigned u) { return __uint_as_float(u << 16); }
__device__ __forceinline__ float bfhi(unsigned u) { return __uint_as_float(u & 0xffff0000u); }

// ---- weight prep + gcur init: blocks 0..127 W1t, 128..255 Wct, 256..259 gcur
__global__ void k_wprep(const float* __restrict__ W1,
                        const float* __restrict__ Wmu, const float* __restrict__ Wls,
                        const float* __restrict__ bmu, const float* __restrict__ bls,
                        unsigned short* __restrict__ W1t,
                        unsigned short* __restrict__ Wct,
                        float* __restrict__ bcat,
                        int* __restrict__ gcur, int nbuck) {
    int b = blockIdx.x, t = threadIdx.x;    // t = k index
    if (b < 128) {
        W1t[b * 128 + t] = (unsigned short)bf16rne(W1[t * 128 + b]);
        if (b == 0) bcat[t] = (t < 64) ? bmu[t] : bls[t - 64];
    } else if (b < 256) {
        int c = b - 128;
        float w = (c < 64) ? Wmu[t * 64 + c] : Wls[t * 64 + (c - 64)];
        Wct[c * 128 + t] = (unsigned short)bf16rne(w);
    } else {
        int idx = (b - 256) * 128 + t;
        if (idx < nbuck) gcur[idx * GPAD] = idx * CAP;
    }
}

// ---- fused: blocks [0,nbb) bucket edges by target/256 into padded segments;
// blocks [nbb,..) run GEMM1 (MFMA): Hbf = bf16(X @ W1), sliced store ----
__global__ __launch_bounds__(256) void k_bg1(
    const int* __restrict__ row, const int* __restrict__ col, int e,
    int* __restrict__ gcur, int* __restrict__ pairs,
    const float* __restrict__ X, const unsigned short* __restrict__ W1t,
    unsigned* __restrict__ Hbf, int n, int nbb)
{
    extern __shared__ char dsm[];
    int tid = threadIdx.x;
    if (blockIdx.x < nbb) {
        // ---------------- bucket pass ----------------
        int* items = (int*)dsm;                                   // 24576 B
        unsigned short* bkt = (unsigned short*)(dsm + 24576);     // 12288 B
        int* hcnt  = (int*)(dsm + 24576 + 12288);                 //  2048 B
        int* lbase = hcnt + NBUCK_MAX;                            //  2048 B
        int e0 = blockIdx.x * EPB;
        int e1 = min(e, e0 + EPB);
        int m = e1 - e0;
        for (int b = tid; b < NBUCK_MAX; b += 256) hcnt[b] = 0;
        __syncthreads();
        for (int i = tid; i < m; i += 256) {
            int s = row[e0 + i];
            int d = col[e0 + i];
            items[i] = (s << BW_SH) | (d & (BW - 1));
            int b = d >> BW_SH;
            bkt[i] = (unsigned short)b;
            atomicAdd(&hcnt[b], 1);
        }
        __syncthreads();
        for (int b = tid; b < NBUCK_MAX; b += 256)
            lbase[b] = hcnt[b] ? atomicAdd(&gcur[b * GPAD], hcnt[b]) : 0;
        __syncthreads();
        for (int i = tid; i < m; i += 256) {
            int pos = atomicAdd(&lbase[bkt[i]], 1);
            pairs[pos] = items[i];
        }
    } else {
        // ---------------- GEMM1 (MFMA) ----------------
        unsigned short* ot = (unsigned short*)dsm;   // [4][16][136] = 17408 B
        int w = tid >> 6, L = tid & 63;
        int q = L >> 4, ml = L & 15;
        int nb0 = (blockIdx.x - nbb) * 64 + w * 16;
        int node = nb0 + ml;
        bool valid = node < n;
        const bf16x8* Bp = (const bf16x8*)W1t;
        f32x4 acc[8];
        #pragma unroll
        for (int cb = 0; cb < 8; ++cb) { acc[cb][0]=0.f; acc[cb][1]=0.f; acc[cb][2]=0.f; acc[cb][3]=0.f; }
        #pragma unroll
        for (int kc = 0; kc < 4; ++kc) {
            bf16x8 af = {0,0,0,0,0,0,0,0};
            if (valid) {
                const float4* xp = (const float4*)&X[(size_t)node * 128 + kc * 32 + q * 8];
                float4 xa = xp[0], xb = xp[1];
                af[0] = (short)bf16rne(xa.x); af[1] = (short)bf16rne(xa.y);
                af[2] = (short)bf16rne(xa.z); af[3] = (short)bf16rne(xa.w);
                af[4] = (short)bf16rne(xb.x); af[5] = (short)bf16rne(xb.y);
                af[6] = (short)bf16rne(xb.z); af[7] = (short)bf16rne(xb.w);
            }
            #pragma unroll
            for (int cb = 0; cb < 8; ++cb) {
                bf16x8 bfr = Bp[(cb * 16 + ml) * 16 + kc * 4 + q];
                acc[cb] = __builtin_amdgcn_mfma_f32_16x16x32_bf16(af, bfr, acc[cb], 0, 0, 0);
            }
        }
        #pragma unroll
        for (int cb = 0; cb < 8; ++cb)
            #pragma unroll
            for (int r = 0; r < 4; ++r)
                ot[(w * 16 + q * 4 + r) * 136 + cb * 16 + ml] =
                    (unsigned short)bf16rne(acc[cb][r]);
        __syncthreads();
        // sliced store: ch chunk cg (8 ch) -> slice cg>>3, word (cg&7)*4
        #pragma unroll
        for (int it = 0; it < 4; ++it) {
            int flat = it * 64 + L;
            int rw = flat >> 4, cg = flat & 15;
            int nd = nb0 + rw;
            if (nd < n) {
                uint4 v = *(const uint4*)&ot[(w * 16 + rw) * 136 + cg * 8];
                *(uint4*)&Hbf[((size_t)(cg >> 3) * n + nd) * 32 + (cg & 7) * 4] = v;
            }
        }
    }
}

// ---- per-bucket hist + wave-shfl scan + LDS scatter; emits cnt/offs/dinv/esrc
__global__ __launch_bounds__(256) void k_fill5(
    const int* __restrict__ gcur, const int* __restrict__ pairs,
    int* __restrict__ offs, int* __restrict__ cnt, float* __restrict__ dinv,
    int* __restrict__ esrc, int n)
{
    __shared__ int lcnt[BW];
    __shared__ int lcur[BW];
    __shared__ int wsum[4];
    __shared__ int lesrc[CAP];
    int b = blockIdx.x, tid = threadIdx.x;
    int t0 = b << BW_SH;
    int nt = min(n - t0, BW);
    int base = b * CAP;
    int m = min(gcur[b * GPAD] - base, CAP);
    lcnt[tid] = 0;
    __syncthreads();
    for (int i = tid; i < m; i += 256)
        atomicAdd(&lcnt[pairs[base + i] & (BW - 1)], 1);
    __syncthreads();
    int s = lcnt[tid];
    // wave-level inclusive scan (64 lanes), then cross-wave prefix
    int x = s;
    #pragma unroll
    for (int d = 1; d < 64; d <<= 1) {
        int t = __shfl_up(x, d);
        if ((tid & 63) >= d) x += t;
    }
    if ((tid & 63) == 63) wsum[tid >> 6] = x;
    __syncthreads();
    int pre = 0;
    #pragma unroll
    for (int i = 0; i < 4; ++i)
        if (i < (tid >> 6)) pre += wsum[i];
    int ex = pre + x - s;             // exclusive scan
    lcur[tid] = ex;
    __syncthreads();
    if (tid < nt) {
        offs[t0 + tid] = base + ex;
        cnt[t0 + tid]  = s;
        dinv[t0 + tid] = 1.0f / sqrtf((float)(s + 1));
    }
    for (int i = tid; i < m; i += 256) {
        int it = pairs[base + i];
        int pos = atomicAdd(&lcur[it & (BW - 1)], 1);
        lesrc[pos] = it >> BW_SH;
    }
    __syncthreads();
    for (int i = tid; i < m; i += 256)
        esrc[base + i] = lesrc[i];
}

// ---- sliced propagation: R11's two-nodes-per-wave engine over a 64-ch
// slice. slice = bid&1 -> slice 0 on XCDs {0,2,4,6}, slice 1 on {1,3,5,7};
// per-XCD gather footprint 12.8 MB. Per-lane gathers are dwords (2 ch);
// 8 gather instrs (2 rows each) in flight per j-step, as in R11. ----
__global__ __launch_bounds__(256) void k_prop_sl(
    const unsigned* __restrict__ hbf, const float* __restrict__ dinv,
    const int* __restrict__ offs, const int* __restrict__ cnt,
    const int* __restrict__ esrc,
    unsigned* __restrict__ out_bf,
    const float* __restrict__ bias, int do_relu, int n)
{
    int sl  = blockIdx.x & 1;
    int wid = (blockIdx.x >> 1) * 4 + (threadIdx.x >> 6);
    int v0  = wid * 2;
    if (v0 >= n) return;
    int v1  = v0 + 1;
    bool hasB = v1 < n;
    int lane = threadIdx.x & 63;
    int half = lane >> 5;
    int fl   = lane & 31;
    const unsigned* rows = hbf + (size_t)sl * n * 32;

    float dvA = dinv[v0];
    int   stA = offs[v0], dgA = cnt[v0];
    float dvB = hasB ? dinv[v1] : 0.f;
    int   stB = hasB ? offs[v1] : 0;
    int   dgB = hasB ? cnt[v1]  : 0;

    float aA0 = 0.f, aA1 = 0.f, aB0 = 0.f, aB1 = 0.f;
    if (half == 0) {                       // self-term A (added once via xor)
        unsigned r = rows[(unsigned)(v0 * 32 + fl)];
        aA0 = dvA * bflo(r); aA1 = dvA * bfhi(r);
    } else if (hasB) {                     // self-term B
        unsigned r = rows[(unsigned)(v1 * 32 + fl)];
        aB0 = dvB * bflo(r); aB1 = dvB * bfhi(r);
    }

    int dmax = max(dgA, dgB);
    for (int base = 0; base < dmax; base += 64) {
        int mA = dgA - base;               // may be <=0
        int mB = dgB - base;
        int sA = 0, sB = 0; float wA = 0.f, wB = 0.f;
        if (lane < mA) {
            sA = __builtin_nontemporal_load(&esrc[stA + base + lane]);
            wA = dinv[sA];
        }
        if (lane < mB) {
            sB = __builtin_nontemporal_load(&esrc[stB + base + lane]);
            wB = dinv[sB];
        }
        int mm = min(max(mA, mB), 64);
        for (int j = 0; j < mm; j += 8) {  // 4A+4B row gathers in flight
            int siA[4], siB[4]; float wiA[4], wiB[4]; unsigned rA[4], rB[4];
            #pragma unroll
            for (int u = 0; u < 4; ++u) {
                siA[u] = __shfl(sA, j + 2 * u + half);
                wiA[u] = __shfl(wA, j + 2 * u + half);
                siB[u] = __shfl(sB, j + 2 * u + half);
                wiB[u] = __shfl(wB, j + 2 * u + half);
            }
            #pragma unroll
            for (int u = 0; u < 4; ++u) {
                rA[u] = rows[(unsigned)(siA[u] * 32 + fl)];
                rB[u] = rows[(unsigned)(siB[u] * 32 + fl)];
            }
            #pragma unroll
            for (int u = 0; u < 4; ++u) {
                aA0 = fmaf(wiA[u], bflo(rA[u]), aA0);
                aA1 = fmaf(wiA[u], bfhi(rA[u]), aA1);
                aB0 = fmaf(wiB[u], bflo(rB[u]), aB0);
                aB1 = fmaf(wiB[u], bfhi(rB[u]), aB1);
            }
        }
    }
    aA0 += __shfl_xor(aA0, 32); aA1 += __shfl_xor(aA1, 32);
    aB0 += __shfl_xor(aB0, 32); aB1 += __shfl_xor(aB1, 32);

    // half0 lanes write node A, half1 lanes write node B (parallel epilogue)
    float c0, c1, dv; int vout;
    if (half == 0) { c0 = aA0; c1 = aA1; dv = dvA; vout = v0; }
    else           { c0 = aB0; c1 = aB1; dv = dvB; vout = v1; }
    if (half == 0 || hasB) {
        c0 *= dv; c1 *= dv;
        if (bias) {
            c0 += bias[sl * 64 + fl * 2 + 0];
            c1 += bias[sl * 64 + fl * 2 + 1];
        }
        if (do_relu) { c0 = fmaxf(c0, 0.f); c1 = fmaxf(c1, 0.f); }
        unsigned pk = (bf16rne(c1) << 16) | bf16rne(c0);
        (out_bf + (size_t)sl * n * 32)[(unsigned)(vout * 32 + fl)] = pk;
    }
}

// ---- GEMM2 (MFMA): out = G @ [Wmu|Wls] + [bmu|bls], sliced A read,
// split fp32 nt write ----
__global__ __launch_bounds__(256) void k_gemm2(
    const unsigned* __restrict__ Gbf, const unsigned short* __restrict__ Wct,
    const float* __restrict__ bcat, float* __restrict__ out, int n)
{
    __shared__ float ot[4][16][132];
    int tid = threadIdx.x;
    int w = tid >> 6, L = tid & 63;
    int q = L >> 4, ml = L & 15;
    int nb0 = blockIdx.x * 64 + w * 16;
    int node = nb0 + ml;
    bool valid = node < n;
    const bf16x8* Ap = (const bf16x8*)Gbf;
    const bf16x8* Bp = (const bf16x8*)Wct;
    f32x4 acc[8];
    #pragma unroll
    for (int cb = 0; cb < 8; ++cb) { acc[cb][0]=0.f; acc[cb][1]=0.f; acc[cb][2]=0.f; acc[cb][3]=0.f; }
    #pragma unroll
    for (int kc = 0; kc < 4; ++kc) {
        bf16x8 af = {0,0,0,0,0,0,0,0};
        if (valid) {
            int cc = kc * 4 + q;    // 8-ch chunk -> slice cc>>3, chunk cc&7
            af = Ap[((size_t)(cc >> 3) * n + node) * 8 + (cc & 7)];
        }
        #pragma unroll
        for (int cb = 0; cb < 8; ++cb) {
            bf16x8 bfr = Bp[(cb * 16 + ml) * 16 + kc * 4 + q];
            acc[cb] = __builtin_amdgcn_mfma_f32_16x16x32_bf16(af, bfr, acc[cb], 0, 0, 0);
        }
    }
    #pragma unroll
    for (int cb = 0; cb < 8; ++cb)
        #pragma unroll
        for (int r = 0; r < 4; ++r)
            ot[w][q * 4 + r][cb * 16 + ml] = acc[cb][r];
    __syncthreads();
    #pragma unroll
    for (int it = 0; it < 8; ++it) {
        int flat = it * 64 + L;
        int row = flat >> 5, c4 = flat & 31;
        int col = c4 * 4;
        int nd = nb0 + row;
        if (nd < n) {
            float4 v = *(const float4*)&ot[w][row][col];
            float4 bb = *(const float4*)&bcat[col];
            f32x4 vv;
            vv[0] = v.x + bb.x; vv[1] = v.y + bb.y;
            vv[2] = v.z + bb.z; vv[3] = v.w + bb.w;
            size_t off = (col < 64)
                ? ((size_t)nd * 64 + col)
                : ((size_t)n * 64 + (size_t)nd * 64 + (col - 64));
            __builtin_nontemporal_store(vv, (f32x4*)&out[off]);
        }
    }
}

extern "C" void kernel_launch(void* const* d_in, const int* in_sizes, int n_in,
                              void* d_out, int out_size, void* d_ws, size_t ws_size,
                              hipStream_t stream) {
    const float* x   = (const float*)d_in[0];
    const int*   ei  = (const int*)d_in[1];
    const float* W1  = (const float*)d_in[3];
    const float* b1  = (const float*)d_in[4];
    const float* Wmu = (const float*)d_in[5];
    const float* bmu = (const float*)d_in[6];
    const float* Wls = (const float*)d_in[7];
    const float* bls = (const float*)d_in[8];
    float* out = (float*)d_out;

    int n = in_sizes[0] / 128;   // 100000
    int e = in_sizes[1] / 2;     // 1600000
    const int* erow = ei;        // sources
    const int* ecol = ei + e;    // targets
    int nbuck = (n + BW - 1) >> BW_SH;        // 391
    int nbb   = (e + EPB - 1) / EPB;          // 261

    char* p = (char*)d_ws;
    auto alloc = [&](size_t bytes) -> char* {
        char* q = p; p += (bytes + 255) & ~(size_t)255; return q;
    };
    int*            gcur  = (int*)           alloc((size_t)NBUCK_MAX * GPAD * 4);
    int*            cnt   = (int*)           alloc((size_t)n * 4);
    int*            offs  = (int*)           alloc((size_t)n * 4);
    float*          dinv  = (float*)         alloc((size_t)n * 4);
    int*            esrc  = (int*)           alloc((size_t)nbuck * CAP * 4);
    unsigned short* W1t   = (unsigned short*)alloc(128 * 128 * 2);
    unsigned short* Wct   = (unsigned short*)alloc(128 * 128 * 2);
    float*          bcat  = (float*)         alloc(128 * 4);
    unsigned*       hbf   = (unsigned*)      alloc((size_t)n * 64 * 4);
    unsigned*       h1bf  = (unsigned*)      alloc((size_t)n * 64 * 4);
    unsigned*       gbf   = (unsigned*)      alloc((size_t)n * 64 * 4);
    int*            pairs = (int*)gbf;   // dead before prop2 writes gbf

    k_wprep<<<260, 128, 0, stream>>>(W1, Wmu, Wls, bmu, bls, W1t, Wct, bcat,
                                     gcur, nbuck);
    k_bg1<<<nbb + (n + 63) / 64, 256, 40960, stream>>>(
        erow, ecol, e, gcur, pairs, x, W1t, hbf, n, nbb);
    k_fill5<<<nbuck, 256, 0, stream>>>(gcur, pairs, offs, cnt, dinv, esrc, n);

    int nwaves = (n + 1) / 2;
    int pblocks = (nwaves + 3) / 4;
    k_prop_sl<<<pblocks * 2, 256, 0, stream>>>(hbf, dinv, offs, cnt, esrc,
                                               h1bf, b1, 1, n);
    k_prop_sl<<<pblocks * 2, 256, 0, stream>>>(h1bf, dinv, offs, cnt, esrc,
                                               gbf, nullptr, 0, n);
    k_gemm2<<<(n + 63) / 64, 256, 0, stream>>>(gbf, Wct, bcat, out, n);
}

// Round 9
// 317.029 us; speedup vs baseline: 1.0701x; 1.0701x over previous
//
#include <hip/hip_runtime.h>
#include <hip/hip_bf16.h>

// ---------------------------------------------------------------------------
// GCN encoder: h1 = relu(P (x W1) + b1); mu = P (h1 Wmu) + bmu; ls likewise.
// P = D^-1/2 (A + I) D^-1/2, in-degree D.
// R14 = R11 (best verified 319.5us; props 62-64us at the random-gather
//   fabric roofline ~3.5TB/s, FETCH 194MB = 8-XCD replication) + three
//   LOCAL non-prop optimizations (no restructure; R12 fusion and R13
//   slicing both regressed and are abandoned):
//   1) k_bg1 bucket pass: per-thread register staging of 24 edges (12 int4),
//      no LDS items/bkt, dynamic LDS 40960->17408 (more blocks/CU for the
//      co-launched GEMM1).
//   2) k_fill5: int4 pairs loads (both phases) + int4 esrc copy-out.
//   3) k_wprep: coalesced loads + scattered stores for both transposes.
//   Slicing post-mortem (R7-R13): L2-fit needs <=16ch slices (3.2MB) but
//   coalescing needs >=64ch rows -> mutually exclusive; closed.
// ---------------------------------------------------------------------------

#define BW_SH   8                 // bucket width = 256 targets
#define BW      (1 << BW_SH)
#define NBUCK_MAX 512             // supports n <= 131072
#define EPB     6144              // edges per bucket-pass block (24/thread)
#define CAP     5120              // per-bucket segment slots (mean 4092, sd 64)
#define GPAD    16                // gcur stride in ints (64B line per counter)

typedef __attribute__((ext_vector_type(8))) short bf16x8;
typedef __attribute__((ext_vector_type(4))) float f32x4;

__device__ __forceinline__ unsigned bf16rne(float f) {   // fp32 -> bf16 bits (RNE)
    unsigned u = __float_as_uint(f);
    return (u + 0x7fffu + ((u >> 16) & 1u)) >> 16;
}
__device__ __forceinline__ float bflo(unsigned u) { return __uint_as_float(u << 16); }
__device__ __forceinline__ float bfhi(unsigned u) { return __uint_as_float(u & 0xffff0000u); }

// ---- weight prep + gcur init: blocks 0..127 W1t, 128..255 Wct, 256..259 gcur
// coalesced loads (block = source row), scattered stores.
__global__ void k_wprep(const float* __restrict__ W1,
                        const float* __restrict__ Wmu, const float* __restrict__ Wls,
                        const float* __restrict__ bmu, const float* __restrict__ bls,
                        unsigned short* __restrict__ W1t,
                        unsigned short* __restrict__ Wct,
                        float* __restrict__ bcat,
                        int* __restrict__ gcur, int nbuck) {
    int b = blockIdx.x, t = threadIdx.x;
    if (b < 128) {
        // W1t[c*128+k] = W1[k*128+c]; here k=b (coalesced read), c=t
        W1t[t * 128 + b] = (unsigned short)bf16rne(W1[b * 128 + t]);
        if (b == 0) bcat[t] = (t < 64) ? bmu[t] : bls[t - 64];
    } else if (b < 256) {
        // Wct[c*128+k] = Wmu/Wls[k*64+(c%64)]; k=b-128 (coalesced), c=t
        int k = b - 128;
        float w = (t < 64) ? Wmu[k * 64 + t] : Wls[k * 64 + (t - 64)];
        Wct[t * 128 + k] = (unsigned short)bf16rne(w);
    } else {
        int idx = (b - 256) * 128 + t;
        if (idx < nbuck) gcur[idx * GPAD] = idx * CAP;
    }
}

// ---- fused: blocks [0,nbb) bucket edges by target/256 into padded segments
// (register-staged, 24 edges/thread); blocks [nbb,..) run GEMM1 (MFMA):
// Hbf = bf16(X @ W1) ----
__global__ __launch_bounds__(256) void k_bg1(
    const int* __restrict__ row, const int* __restrict__ col, int e,
    int* __restrict__ gcur, int* __restrict__ pairs,
    const float* __restrict__ X, const unsigned short* __restrict__ W1t,
    unsigned* __restrict__ Hbf, int n, int nbb)
{
    extern __shared__ char dsm[];
    int tid = threadIdx.x;
    if (blockIdx.x < nbb) {
        // ---------------- bucket pass (register staging) ----------------
        int* hcnt  = (int*)dsm;                  // 2048 B
        int* lbase = hcnt + NBUCK_MAX;           // 2048 B
        int e0 = blockIdx.x * EPB;
        int m  = min(e - e0, EPB);
        int m4 = m >> 2;                         // EPB%4==0, e%4==0 -> m%4==0
        const int4* r4p = (const int4*)(row + e0);
        const int4* c4p = (const int4*)(col + e0);
        int4 rr[6], cc[6];
        #pragma unroll
        for (int it = 0; it < 6; ++it) {
            int i = it * 256 + tid;
            if (i < m4) { rr[it] = r4p[i]; cc[it] = c4p[i]; }
            else        { cc[it] = make_int4(-1, -1, -1, -1); }
        }
        for (int b = tid; b < NBUCK_MAX; b += 256) hcnt[b] = 0;
        __syncthreads();
        #pragma unroll
        for (int it = 0; it < 6; ++it) {
            if (cc[it].x >= 0) atomicAdd(&hcnt[cc[it].x >> BW_SH], 1);
            if (cc[it].y >= 0) atomicAdd(&hcnt[cc[it].y >> BW_SH], 1);
            if (cc[it].z >= 0) atomicAdd(&hcnt[cc[it].z >> BW_SH], 1);
            if (cc[it].w >= 0) atomicAdd(&hcnt[cc[it].w >> BW_SH], 1);
        }
        __syncthreads();
        for (int b = tid; b < NBUCK_MAX; b += 256)
            lbase[b] = hcnt[b] ? atomicAdd(&gcur[b * GPAD], hcnt[b]) : 0;
        __syncthreads();
        #pragma unroll
        for (int it = 0; it < 6; ++it) {
            int4 c4 = cc[it], r4 = rr[it];
            int pos;
            if (c4.x >= 0) {
                pos = atomicAdd(&lbase[c4.x >> BW_SH], 1);
                pairs[pos] = (r4.x << BW_SH) | (c4.x & (BW - 1));
            }
            if (c4.y >= 0) {
                pos = atomicAdd(&lbase[c4.y >> BW_SH], 1);
                pairs[pos] = (r4.y << BW_SH) | (c4.y & (BW - 1));
            }
            if (c4.z >= 0) {
                pos = atomicAdd(&lbase[c4.z >> BW_SH], 1);
                pairs[pos] = (r4.z << BW_SH) | (c4.z & (BW - 1));
            }
            if (c4.w >= 0) {
                pos = atomicAdd(&lbase[c4.w >> BW_SH], 1);
                pairs[pos] = (r4.w << BW_SH) | (c4.w & (BW - 1));
            }
        }
        // scalar tail (empty when m%4==0; kept for robustness)
        for (int i = (m4 << 2) + tid; i < m; i += 256) {
            int c = col[e0 + i], r = row[e0 + i];
            int pos = atomicAdd(&lbase[c >> BW_SH], 1);
            pairs[pos] = (r << BW_SH) | (c & (BW - 1));
        }
    } else {
        // ---------------- GEMM1 (MFMA) ----------------
        unsigned short* ot = (unsigned short*)dsm;   // [4][16][136] = 17408 B
        int w = tid >> 6, L = tid & 63;
        int q = L >> 4, ml = L & 15;
        int nb0 = (blockIdx.x - nbb) * 64 + w * 16;
        int node = nb0 + ml;
        bool valid = node < n;
        const bf16x8* Bp = (const bf16x8*)W1t;
        f32x4 acc[8];
        #pragma unroll
        for (int cb = 0; cb < 8; ++cb) { acc[cb][0]=0.f; acc[cb][1]=0.f; acc[cb][2]=0.f; acc[cb][3]=0.f; }
        #pragma unroll
        for (int kc = 0; kc < 4; ++kc) {
            bf16x8 af = {0,0,0,0,0,0,0,0};
            if (valid) {
                const float4* xp = (const float4*)&X[(size_t)node * 128 + kc * 32 + q * 8];
                float4 xa = xp[0], xb = xp[1];
                af[0] = (short)bf16rne(xa.x); af[1] = (short)bf16rne(xa.y);
                af[2] = (short)bf16rne(xa.z); af[3] = (short)bf16rne(xa.w);
                af[4] = (short)bf16rne(xb.x); af[5] = (short)bf16rne(xb.y);
                af[6] = (short)bf16rne(xb.z); af[7] = (short)bf16rne(xb.w);
            }
            #pragma unroll
            for (int cb = 0; cb < 8; ++cb) {
                bf16x8 bfr = Bp[(cb * 16 + ml) * 16 + kc * 4 + q];
                acc[cb] = __builtin_amdgcn_mfma_f32_16x16x32_bf16(af, bfr, acc[cb], 0, 0, 0);
            }
        }
        #pragma unroll
        for (int cb = 0; cb < 8; ++cb)
            #pragma unroll
            for (int r = 0; r < 4; ++r)
                ot[(w * 16 + q * 4 + r) * 136 + cb * 16 + ml] =
                    (unsigned short)bf16rne(acc[cb][r]);
        __syncthreads();
        #pragma unroll
        for (int it = 0; it < 4; ++it) {
            int flat = it * 64 + L;
            int rw = flat >> 4, cg = flat & 15;
            int nd = nb0 + rw;
            if (nd < n) {
                uint4 v = *(const uint4*)&ot[(w * 16 + rw) * 136 + cg * 8];
                *(uint4*)&Hbf[(size_t)nd * 64 + cg * 4] = v;
            }
        }
    }
}

// ---- per-bucket hist + wave-shfl scan + LDS scatter; int4 IO;
// emits cnt/offs/dinv/esrc ----
__global__ __launch_bounds__(256) void k_fill5(
    const int* __restrict__ gcur, const int* __restrict__ pairs,
    int* __restrict__ offs, int* __restrict__ cnt, float* __restrict__ dinv,
    int* __restrict__ esrc, int n)
{
    __shared__ int lcnt[BW];
    __shared__ int lcur[BW];
    __shared__ int wsum[4];
    __shared__ int lesrc[CAP];
    int b = blockIdx.x, tid = threadIdx.x;
    int t0 = b << BW_SH;
    int nt = min(n - t0, BW);
    int base = b * CAP;
    int m = min(gcur[b * GPAD] - base, CAP);
    lcnt[tid] = 0;
    __syncthreads();
    int m4 = m >> 2;
    const int4* p4 = (const int4*)(pairs + base);
    for (int i = tid; i < m4; i += 256) {
        int4 v = p4[i];
        atomicAdd(&lcnt[v.x & (BW - 1)], 1);
        atomicAdd(&lcnt[v.y & (BW - 1)], 1);
        atomicAdd(&lcnt[v.z & (BW - 1)], 1);
        atomicAdd(&lcnt[v.w & (BW - 1)], 1);
    }
    for (int i = (m4 << 2) + tid; i < m; i += 256)
        atomicAdd(&lcnt[pairs[base + i] & (BW - 1)], 1);
    __syncthreads();
    int s = lcnt[tid];
    // wave-level inclusive scan (64 lanes), then cross-wave prefix
    int x = s;
    #pragma unroll
    for (int d = 1; d < 64; d <<= 1) {
        int t = __shfl_up(x, d);
        if ((tid & 63) >= d) x += t;
    }
    if ((tid & 63) == 63) wsum[tid >> 6] = x;
    __syncthreads();
    int pre = 0;
    #pragma unroll
    for (int i = 0; i < 4; ++i)
        if (i < (tid >> 6)) pre += wsum[i];
    int ex = pre + x - s;             // exclusive scan
    lcur[tid] = ex;
    __syncthreads();
    if (tid < nt) {
        offs[t0 + tid] = base + ex;
        cnt[t0 + tid]  = s;
        dinv[t0 + tid] = 1.0f / sqrtf((float)(s + 1));
    }
    for (int i = tid; i < m4; i += 256) {
        int4 v = p4[i];
        int pos;
        pos = atomicAdd(&lcur[v.x & (BW - 1)], 1); lesrc[pos] = v.x >> BW_SH;
        pos = atomicAdd(&lcur[v.y & (BW - 1)], 1); lesrc[pos] = v.y >> BW_SH;
        pos = atomicAdd(&lcur[v.z & (BW - 1)], 1); lesrc[pos] = v.z >> BW_SH;
        pos = atomicAdd(&lcur[v.w & (BW - 1)], 1); lesrc[pos] = v.w >> BW_SH;
    }
    for (int i = (m4 << 2) + tid; i < m; i += 256) {
        int it = pairs[base + i];
        int pos = atomicAdd(&lcur[it & (BW - 1)], 1);
        lesrc[pos] = it >> BW_SH;
    }
    __syncthreads();
    int mc = (m + 3) >> 2;            // CAP padding absorbs overread
    int4* e4 = (int4*)(esrc + base);
    const int4* l4 = (const int4*)lesrc;
    for (int i = tid; i < mc; i += 256) e4[i] = l4[i];
}

// ---- propagation over bf16 table: TWO nodes per wave (A on half0, B on
// half1 for self/write), edge bursts interleaved 4A+4B (8 full-row gather
// instrs in flight), zero-padded s/w replaces the tail ladder. ----
__global__ __launch_bounds__(256) void k_prop_bf2(
    const unsigned* __restrict__ hbf, const float* __restrict__ dinv,
    const int* __restrict__ offs, const int* __restrict__ cnt,
    const int* __restrict__ esrc,
    unsigned* __restrict__ out_bf,
    const float* __restrict__ bias, int do_relu, int n)
{
    int wid = (blockIdx.x * blockDim.x + threadIdx.x) >> 6;
    int v0  = wid * 2;
    if (v0 >= n) return;
    int v1  = v0 + 1;
    bool hasB = v1 < n;
    int lane = threadIdx.x & 63;
    int half = lane >> 5;
    int fl   = lane & 31;
    const uint2* rows = (const uint2*)hbf;

    float dvA = dinv[v0];
    int   stA = offs[v0], dgA = cnt[v0];
    float dvB = hasB ? dinv[v1] : 0.f;
    int   stB = hasB ? offs[v1] : 0;
    int   dgB = hasB ? cnt[v1]  : 0;

    float aA0=0.f,aA1=0.f,aA2=0.f,aA3=0.f;
    float aB0=0.f,aB1=0.f,aB2=0.f,aB3=0.f;
    if (half == 0) {                       // self-term A (added once via xor)
        uint2 r = rows[(size_t)v0 * 32 + fl];
        aA0 = dvA * bflo(r.x); aA1 = dvA * bfhi(r.x);
        aA2 = dvA * bflo(r.y); aA3 = dvA * bfhi(r.y);
    } else if (hasB) {                     // self-term B
        uint2 r = rows[(size_t)v1 * 32 + fl];
        aB0 = dvB * bflo(r.x); aB1 = dvB * bfhi(r.x);
        aB2 = dvB * bflo(r.y); aB3 = dvB * bfhi(r.y);
    }

    int dmax = max(dgA, dgB);
    for (int base = 0; base < dmax; base += 64) {
        int mA = dgA - base;               // may be <=0
        int mB = dgB - base;
        int sA = 0, sB = 0; float wA = 0.f, wB = 0.f;
        if (lane < mA) { sA = esrc[stA + base + lane]; wA = dinv[sA]; }
        if (lane < mB) { sB = esrc[stB + base + lane]; wB = dinv[sB]; }
        int mm = min(max(mA, mB), 64);
        for (int j = 0; j < mm; j += 8) {  // 4A+4B full-row gathers in flight
            int siA[4], siB[4]; float wiA[4], wiB[4]; uint2 rA[4], rB[4];
            #pragma unroll
            for (int u = 0; u < 4; ++u) {
                siA[u] = __shfl(sA, j + 2 * u + half);
                wiA[u] = __shfl(wA, j + 2 * u + half);
                siB[u] = __shfl(sB, j + 2 * u + half);
                wiB[u] = __shfl(wB, j + 2 * u + half);
            }
            #pragma unroll
            for (int u = 0; u < 4; ++u) {
                rA[u] = rows[(size_t)siA[u] * 32 + fl];
                rB[u] = rows[(size_t)siB[u] * 32 + fl];
            }
            #pragma unroll
            for (int u = 0; u < 4; ++u) {
                aA0 = fmaf(wiA[u], bflo(rA[u].x), aA0);
                aA1 = fmaf(wiA[u], bfhi(rA[u].x), aA1);
                aA2 = fmaf(wiA[u], bflo(rA[u].y), aA2);
                aA3 = fmaf(wiA[u], bfhi(rA[u].y), aA3);
                aB0 = fmaf(wiB[u], bflo(rB[u].x), aB0);
                aB1 = fmaf(wiB[u], bfhi(rB[u].x), aB1);
                aB2 = fmaf(wiB[u], bflo(rB[u].y), aB2);
                aB3 = fmaf(wiB[u], bfhi(rB[u].y), aB3);
            }
        }
    }
    aA0 += __shfl_xor(aA0, 32); aA1 += __shfl_xor(aA1, 32);
    aA2 += __shfl_xor(aA2, 32); aA3 += __shfl_xor(aA3, 32);
    aB0 += __shfl_xor(aB0, 32); aB1 += __shfl_xor(aB1, 32);
    aB2 += __shfl_xor(aB2, 32); aB3 += __shfl_xor(aB3, 32);

    // half0 lanes write node A, half1 lanes write node B (parallel epilogue)
    float c0, c1, c2, c3, dv; int vout;
    if (half == 0) { c0=aA0; c1=aA1; c2=aA2; c3=aA3; dv=dvA; vout=v0; }
    else           { c0=aB0; c1=aB1; c2=aB2; c3=aB3; dv=dvB; vout=v1; }
    if (half == 0 || hasB) {
        c0 *= dv; c1 *= dv; c2 *= dv; c3 *= dv;
        if (bias) {
            c0 += bias[fl * 4 + 0]; c1 += bias[fl * 4 + 1];
            c2 += bias[fl * 4 + 2]; c3 += bias[fl * 4 + 3];
        }
        if (do_relu) {
            c0 = fmaxf(c0, 0.f); c1 = fmaxf(c1, 0.f);
            c2 = fmaxf(c2, 0.f); c3 = fmaxf(c3, 0.f);
        }
        uint2 pk;
        pk.x = (bf16rne(c1) << 16) | bf16rne(c0);
        pk.y = (bf16rne(c3) << 16) | bf16rne(c2);
        ((uint2*)out_bf)[(size_t)vout * 32 + fl] = pk;
    }
}

// ---- GEMM2 (MFMA): out = G @ [Wmu|Wls] + [bmu|bls], split fp32 nt write ----
__global__ __launch_bounds__(256) void k_gemm2(
    const unsigned* __restrict__ Gbf, const unsigned short* __restrict__ Wct,
    const float* __restrict__ bcat, float* __restrict__ out, int n)
{
    __shared__ float ot[4][16][132];
    int tid = threadIdx.x;
    int w = tid >> 6, L = tid & 63;
    int q = L >> 4, ml = L & 15;
    int nb0 = blockIdx.x * 64 + w * 16;
    int node = nb0 + ml;
    bool valid = node < n;
    const bf16x8* Ap = (const bf16x8*)Gbf;
    const bf16x8* Bp = (const bf16x8*)Wct;
    f32x4 acc[8];
    #pragma unroll
    for (int cb = 0; cb < 8; ++cb) { acc[cb][0]=0.f; acc[cb][1]=0.f; acc[cb][2]=0.f; acc[cb][3]=0.f; }
    #pragma unroll
    for (int kc = 0; kc < 4; ++kc) {
        bf16x8 af = {0,0,0,0,0,0,0,0};
        if (valid) af = Ap[(size_t)node * 16 + kc * 4 + q];
        #pragma unroll
        for (int cb = 0; cb < 8; ++cb) {
            bf16x8 bfr = Bp[(cb * 16 + ml) * 16 + kc * 4 + q];
            acc[cb] = __builtin_amdgcn_mfma_f32_16x16x32_bf16(af, bfr, acc[cb], 0, 0, 0);
        }
    }
    #pragma unroll
    for (int cb = 0; cb < 8; ++cb)
        #pragma unroll
        for (int r = 0; r < 4; ++r)
            ot[w][q * 4 + r][cb * 16 + ml] = acc[cb][r];
    __syncthreads();
    #pragma unroll
    for (int it = 0; it < 8; ++it) {
        int flat = it * 64 + L;
        int row = flat >> 5, c4 = flat & 31;
        int col = c4 * 4;
        int nd = nb0 + row;
        if (nd < n) {
            float4 v = *(const float4*)&ot[w][row][col];
            float4 bb = *(const float4*)&bcat[col];
            f32x4 vv;
            vv[0] = v.x + bb.x; vv[1] = v.y + bb.y;
            vv[2] = v.z + bb.z; vv[3] = v.w + bb.w;
            size_t off = (col < 64)
                ? ((size_t)nd * 64 + col)
                : ((size_t)n * 64 + (size_t)nd * 64 + (col - 64));
            __builtin_nontemporal_store(vv, (f32x4*)&out[off]);
        }
    }
}

extern "C" void kernel_launch(void* const* d_in, const int* in_sizes, int n_in,
                              void* d_out, int out_size, void* d_ws, size_t ws_size,
                              hipStream_t stream) {
    const float* x   = (const float*)d_in[0];
    const int*   ei  = (const int*)d_in[1];
    const float* W1  = (const float*)d_in[3];
    const float* b1  = (const float*)d_in[4];
    const float* Wmu = (const float*)d_in[5];
    const float* bmu = (const float*)d_in[6];
    const float* Wls = (const float*)d_in[7];
    const float* bls = (const float*)d_in[8];
    float* out = (float*)d_out;

    int n = in_sizes[0] / 128;   // 100000
    int e = in_sizes[1] / 2;     // 1600000
    const int* erow = ei;        // sources
    const int* ecol = ei + e;    // targets
    int nbuck = (n + BW - 1) >> BW_SH;        // 391
    int nbb   = (e + EPB - 1) / EPB;          // 261

    char* p = (char*)d_ws;
    auto alloc = [&](size_t bytes) -> char* {
        char* q = p; p += (bytes + 255) & ~(size_t)255; return q;
    };
    int*            gcur  = (int*)           alloc((size_t)NBUCK_MAX * GPAD * 4);
    int*            cnt   = (int*)           alloc((size_t)n * 4);
    int*            offs  = (int*)           alloc((size_t)n * 4);
    float*          dinv  = (float*)         alloc((size_t)n * 4);
    int*            esrc  = (int*)           alloc((size_t)nbuck * CAP * 4);
    unsigned short* W1t   = (unsigned short*)alloc(128 * 128 * 2);
    unsigned short* Wct   = (unsigned short*)alloc(128 * 128 * 2);
    float*          bcat  = (float*)         alloc(128 * 4);
    unsigned*       hbf   = (unsigned*)      alloc((size_t)n * 64 * 4);
    unsigned*       h1bf  = (unsigned*)      alloc((size_t)n * 64 * 4);
    unsigned*       gbf   = (unsigned*)      alloc((size_t)n * 64 * 4);
    int*            pairs = (int*)gbf;   // dead before prop2 writes gbf

    k_wprep<<<260, 128, 0, stream>>>(W1, Wmu, Wls, bmu, bls, W1t, Wct, bcat,
                                     gcur, nbuck);
    k_bg1<<<nbb + (n + 63) / 64, 256, 17408, stream>>>(
        erow, ecol, e, gcur, pairs, x, W1t, hbf, n, nbb);
    k_fill5<<<nbuck, 256, 0, stream>>>(gcur, pairs, offs, cnt, dinv, esrc, n);

    int nwaves = (n + 1) / 2;
    int pblocks = (nwaves + 3) / 4;
    k_prop_bf2<<<pblocks, 256, 0, stream>>>(hbf, dinv, offs, cnt, esrc,
                                            h1bf, b1, 1, n);
    k_prop_bf2<<<pblocks, 256, 0, stream>>>(h1bf, dinv, offs, cnt, esrc,
                                            gbf, nullptr, 0, n);
    k_gemm2<<<(n + 63) / 64, 256, 0, stream>>>(gbf, Wct, bcat, out, n);
}